// Round 2
// baseline (36.132 us; speedup 1.0000x reference)
//
#include <hip/hip_runtime.h>

// PerPixelConv: out[b,0,h,w] = sum_{kw,kh} kernel[b, kw*3+kh, h, w] * padded_img[b, h+kh, w+kw]
// B=16, K2=9 (k=3, pad=1), H=W=512, fp32.
// Memory-bound: kernel tensor (151 MB, read exactly once) dominates. Strategy:
//  - 1 thread per output float4, kernel reads as nontemporal float4 (don't pollute L2),
//  - image neighborhood via 1 aligned float4 + 2 edge scalars per row (wave-uniform
//    row-validity branches; a wave's 64 lanes share the same h since 128 slots/row),
//  - nontemporal float4 store for output (never re-read).

#define PPC_B 16
#define PPC_K2 9
#define PPC_H 512
#define PPC_W 512

typedef float f4 __attribute__((ext_vector_type(4)));

__global__ __launch_bounds__(256) void PerPixelConv_kernel(
    const float* __restrict__ kern,   // [B, 9, H, W]
    const float* __restrict__ img,    // [B, 1, H, W]
    float* __restrict__ out)          // [B, 1, H, W]
{
    const int W4 = PPC_W / 4;                       // 128 float4 per row
    int gid = blockIdx.x * blockDim.x + threadIdx.x;

    const int w4 = (gid & (W4 - 1)) * 4;            // starting w of this thread's 4 pixels
    const int h  = (gid >> 7) & (PPC_H - 1);
    const int b  = gid >> 16;                       // gid / (128*512)

    const size_t plane = (size_t)PPC_H * PPC_W;     // 262144
    const float* kb = kern + (size_t)b * PPC_K2 * plane + (size_t)h * PPC_W + w4;
    const float* ib = img  + (size_t)b * plane;

    // Image neighborhood rows h-1..h+1, cols w4-1..w4+4 (zero-padded).
    // Per row: one aligned float4 (cols w4..w4+3) + two edge scalars.
    float im[3][6];
#pragma unroll
    for (int r = 0; r < 3; ++r) {
        const int ih = h + r - 1;
        const bool rv = (ih >= 0) && (ih < PPC_H);   // wave-uniform
        const float* row = ib + (size_t)ih * PPC_W;
        f4 c = {0.f, 0.f, 0.f, 0.f};
        float l = 0.f, rr = 0.f;
        if (rv) {
            c = *reinterpret_cast<const f4*>(row + w4);
            if (w4 > 0)            l  = row[w4 - 1];
            if (w4 + 4 < PPC_W)    rr = row[w4 + 4];
        }
        im[r][0] = l;   im[r][1] = c.x; im[r][2] = c.y;
        im[r][3] = c.z; im[r][4] = c.w; im[r][5] = rr;
    }

    // Prefetch all 9 kernel float4s (nontemporal: read-once stream, keep L2 for image).
    f4 kv[9];
#pragma unroll
    for (int idx = 0; idx < 9; ++idx) {
        kv[idx] = __builtin_nontemporal_load(
            reinterpret_cast<const f4*>(kb + (size_t)idx * plane));
    }

    f4 acc = {0.f, 0.f, 0.f, 0.f};
#pragma unroll
    for (int kw = 0; kw < 3; ++kw) {
#pragma unroll
        for (int kh = 0; kh < 3; ++kh) {
            const int idx = kw * 3 + kh;
            // output pixel (h, w4+j) uses image[h+kh-1][w4+j+kw-1] = im[kh][j+kw]
            acc.x = fmaf(kv[idx].x, im[kh][0 + kw], acc.x);
            acc.y = fmaf(kv[idx].y, im[kh][1 + kw], acc.y);
            acc.z = fmaf(kv[idx].z, im[kh][2 + kw], acc.z);
            acc.w = fmaf(kv[idx].w, im[kh][3 + kw], acc.w);
        }
    }

    __builtin_nontemporal_store(acc,
        reinterpret_cast<f4*>(out + (size_t)b * plane + (size_t)h * PPC_W + w4));
}

extern "C" void kernel_launch(void* const* d_in, const int* in_sizes, int n_in,
                              void* d_out, int out_size, void* d_ws, size_t ws_size,
                              hipStream_t stream) {
    const float* kern = (const float*)d_in[0];  // [16, 9, 512, 512]
    const float* img  = (const float*)d_in[1];  // [16, 1, 512, 512]
    float* out = (float*)d_out;                 // [16, 1, 512, 512]

    const int total = PPC_B * PPC_H * (PPC_W / 4);  // 1,048,576 threads
    const int block = 256;
    const int grid = total / block;                 // 4096 blocks
    PerPixelConv_kernel<<<grid, block, 0, stream>>>(kern, img, out);
}

// Round 3
// 34.740 us; speedup vs baseline: 1.0401x; 1.0401x over previous
//
#include <hip/hip_runtime.h>

// PerPixelConv: out[b,0,h,w] = sum_{kw,kh} kernel[b, kw*3+kh, h, w] * padded_img[b, h+kh, w+kw]
// B=16, K2=9 (k=3, pad=1), H=W=512, fp32.
// Memory-bound: kernel tensor (151 MB, read exactly once) dominates; ~185 MB total
// -> ~29 us floor at 6.3 TB/s. R2 post-mortem: nontemporal loads on the kernel
// stream REGRESSED (36.1 vs 33.9 us) -- keep plain cached loads (L2/L3 absorb and
// smooth the stream). Keep the reduced-VMEM image path (f4 + 2 edge scalars per row,
// wave-uniform row validity), and issue kernel loads first to overlap their HBM
// latency with the cache-hit image loads.

#define PPC_B 16
#define PPC_K2 9
#define PPC_H 512
#define PPC_W 512

typedef float f4 __attribute__((ext_vector_type(4)));

__global__ __launch_bounds__(256) void PerPixelConv_kernel(
    const float* __restrict__ kern,   // [B, 9, H, W]
    const float* __restrict__ img,    // [B, 1, H, W]
    float* __restrict__ out)          // [B, 1, H, W]
{
    const int W4 = PPC_W / 4;                       // 128 float4 per row
    int gid = blockIdx.x * blockDim.x + threadIdx.x;

    const int w4 = (gid & (W4 - 1)) * 4;            // starting w of this thread's 4 pixels
    const int h  = (gid >> 7) & (PPC_H - 1);
    const int b  = gid >> 16;                       // gid / (128*512)

    const size_t plane = (size_t)PPC_H * PPC_W;     // 262144
    const float* kb = kern + (size_t)b * PPC_K2 * plane + (size_t)h * PPC_W + w4;
    const float* ib = img  + (size_t)b * plane;

    // Issue the 9 kernel float4 loads first: these are the HBM-miss stream;
    // their latency overlaps the (mostly cache-hit) image loads below.
    f4 kv[9];
#pragma unroll
    for (int idx = 0; idx < 9; ++idx)
        kv[idx] = *reinterpret_cast<const f4*>(kb + (size_t)idx * plane);

    // Image neighborhood rows h-1..h+1, cols w4-1..w4+4 (zero-padded).
    // Per row: one aligned float4 (cols w4..w4+3) + two edge scalars.
    float im[3][6];
#pragma unroll
    for (int r = 0; r < 3; ++r) {
        const int ih = h + r - 1;
        const bool rv = (ih >= 0) && (ih < PPC_H);   // wave-uniform
        const float* row = ib + (size_t)ih * PPC_W;
        f4 c = {0.f, 0.f, 0.f, 0.f};
        float l = 0.f, rr = 0.f;
        if (rv) {
            c = *reinterpret_cast<const f4*>(row + w4);
            if (w4 > 0)            l  = row[w4 - 1];
            if (w4 + 4 < PPC_W)    rr = row[w4 + 4];
        }
        im[r][0] = l;   im[r][1] = c.x; im[r][2] = c.y;
        im[r][3] = c.z; im[r][4] = c.w; im[r][5] = rr;
    }

    f4 acc = {0.f, 0.f, 0.f, 0.f};
#pragma unroll
    for (int kw = 0; kw < 3; ++kw) {
#pragma unroll
        for (int kh = 0; kh < 3; ++kh) {
            const int idx = kw * 3 + kh;
            // output pixel (h, w4+j) uses image[h+kh-1][w4+j+kw-1] = im[kh][j+kw]
            acc.x = fmaf(kv[idx].x, im[kh][0 + kw], acc.x);
            acc.y = fmaf(kv[idx].y, im[kh][1 + kw], acc.y);
            acc.z = fmaf(kv[idx].z, im[kh][2 + kw], acc.z);
            acc.w = fmaf(kv[idx].w, im[kh][3 + kw], acc.w);
        }
    }

    *reinterpret_cast<f4*>(out + (size_t)b * plane + (size_t)h * PPC_W + w4) = acc;
}

extern "C" void kernel_launch(void* const* d_in, const int* in_sizes, int n_in,
                              void* d_out, int out_size, void* d_ws, size_t ws_size,
                              hipStream_t stream) {
    const float* kern = (const float*)d_in[0];  // [16, 9, 512, 512]
    const float* img  = (const float*)d_in[1];  // [16, 1, 512, 512]
    float* out = (float*)d_out;                 // [16, 1, 512, 512]

    const int total = PPC_B * PPC_H * (PPC_W / 4);  // 1,048,576 threads
    const int block = 256;
    const int grid = total / block;                 // 4096 blocks
    PerPixelConv_kernel<<<grid, block, 0, stream>>>(kern, img, out);
}

// Round 4
// 31.835 us; speedup vs baseline: 1.1350x; 1.0912x over previous
//
#include <hip/hip_runtime.h>

// PerPixelConv: out[b,0,h,w] = sum_{kw,kh} kernel[b, kw*3+kh, h, w] * padded_img[b, h+kh, w+kw]
// B=16, K2=9 (k=3, pad=1), H=W=512, fp32.
// Memory-bound: kernel tensor (151 MB, read once) dominates; ~185 MB ideal traffic.
// R2: nontemporal on the kernel stream regressed (36.1) -> keep cached loads.
// R3: image-path restructure neutral (34.7 vs 33.9 ~ noise).
// R4 (this): XCD-aware block swizzle. Adjacent blocks share image rows (each block
// = 2 rows of one b; needs rows 2g-1..2g+2). HW round-robins blocks across 8 XCDs,
// so sharers land on different (non-coherent) L2s. Swizzle gives each XCD a
// contiguous 512-block chunk (= 2 full b-planes, 2 MB image working set -> fits
// 4 MB per-XCD L2), turning image re-reads into L2 hits.

#define PPC_B 16
#define PPC_K2 9
#define PPC_H 512
#define PPC_W 512

typedef float f4 __attribute__((ext_vector_type(4)));

__global__ __launch_bounds__(256) void PerPixelConv_kernel(
    const float* __restrict__ kern,   // [B, 9, H, W]
    const float* __restrict__ img,    // [B, 1, H, W]
    float* __restrict__ out)          // [B, 1, H, W]
{
    // Bijective XCD swizzle: 4096 blocks, 8 XCDs, 512-block contiguous chunk each.
    const int bid = ((blockIdx.x & 7) << 9) | (blockIdx.x >> 3);
    int gid = bid * blockDim.x + threadIdx.x;

    const int W4 = PPC_W / 4;                       // 128 float4 per row
    const int w4 = (gid & (W4 - 1)) * 4;            // starting w of this thread's 4 pixels
    const int h  = (gid >> 7) & (PPC_H - 1);
    const int b  = gid >> 16;                       // gid / (128*512)

    const size_t plane = (size_t)PPC_H * PPC_W;     // 262144
    const float* kb = kern + (size_t)b * PPC_K2 * plane + (size_t)h * PPC_W + w4;
    const float* ib = img  + (size_t)b * plane;

    // Issue the 9 kernel float4 loads first: HBM-miss stream; latency overlaps
    // the (mostly cache-hit) image loads below.
    f4 kv[9];
#pragma unroll
    for (int idx = 0; idx < 9; ++idx)
        kv[idx] = *reinterpret_cast<const f4*>(kb + (size_t)idx * plane);

    // Image neighborhood rows h-1..h+1, cols w4-1..w4+4 (zero-padded).
    // Per row: one aligned float4 (cols w4..w4+3) + two edge scalars.
    float im[3][6];
#pragma unroll
    for (int r = 0; r < 3; ++r) {
        const int ih = h + r - 1;
        const bool rv = (ih >= 0) && (ih < PPC_H);   // wave-uniform
        const float* row = ib + (size_t)ih * PPC_W;
        f4 c = {0.f, 0.f, 0.f, 0.f};
        float l = 0.f, rr = 0.f;
        if (rv) {
            c = *reinterpret_cast<const f4*>(row + w4);
            if (w4 > 0)            l  = row[w4 - 1];
            if (w4 + 4 < PPC_W)    rr = row[w4 + 4];
        }
        im[r][0] = l;   im[r][1] = c.x; im[r][2] = c.y;
        im[r][3] = c.z; im[r][4] = c.w; im[r][5] = rr;
    }

    f4 acc = {0.f, 0.f, 0.f, 0.f};
#pragma unroll
    for (int kw = 0; kw < 3; ++kw) {
#pragma unroll
        for (int kh = 0; kh < 3; ++kh) {
            const int idx = kw * 3 + kh;
            // output pixel (h, w4+j) uses image[h+kh-1][w4+j+kw-1] = im[kh][j+kw]
            acc.x = fmaf(kv[idx].x, im[kh][0 + kw], acc.x);
            acc.y = fmaf(kv[idx].y, im[kh][1 + kw], acc.y);
            acc.z = fmaf(kv[idx].z, im[kh][2 + kw], acc.z);
            acc.w = fmaf(kv[idx].w, im[kh][3 + kw], acc.w);
        }
    }

    *reinterpret_cast<f4*>(out + (size_t)b * plane + (size_t)h * PPC_W + w4) = acc;
}

extern "C" void kernel_launch(void* const* d_in, const int* in_sizes, int n_in,
                              void* d_out, int out_size, void* d_ws, size_t ws_size,
                              hipStream_t stream) {
    const float* kern = (const float*)d_in[0];  // [16, 9, 512, 512]
    const float* img  = (const float*)d_in[1];  // [16, 1, 512, 512]
    float* out = (float*)d_out;                 // [16, 1, 512, 512]

    const int total = PPC_B * PPC_H * (PPC_W / 4);  // 1,048,576 threads
    const int block = 256;
    const int grid = total / block;                 // 4096 blocks
    PerPixelConv_kernel<<<grid, block, 0, stream>>>(kern, img, out);
}

// Round 5
// 30.971 us; speedup vs baseline: 1.1666x; 1.0279x over previous
//
#include <hip/hip_runtime.h>

// PerPixelConv: out[b,0,h,w] = sum_{kw,kh} kernel[b, kw*3+kh, h, w] * padded_img[b, h+kh, w+kw]
// B=16, K2=9 (k=3, pad=1), H=W=512, fp32.
// Memory-bound: kernel tensor (151 MB, read once) dominates; ~185 MB ideal traffic,
// floor ~29.4 us at the 6.29 TB/s measured copy ceiling.
// R2: nontemporal on the kernel stream regressed -> cached loads.
// R3: image-path restructure neutral.
// R4: XCD swizzle WIN (34.7 -> 31.8): per-XCD contiguous chunks make image
//     row-sharing L2-local (2 b-planes = 2 MB per XCD L2).
// R5 (this): 8 px/thread. Halves edge-scalar loads per byte, doubles per-thread
//     MLP (18 kernel f4 in flight). One wave = one image row (64 x 8 = 512) so
//     row validity stays wave-uniform. Grid 2048, swizzle chunk 256 (= 2 b-planes).

#define PPC_B 16
#define PPC_K2 9
#define PPC_H 512
#define PPC_W 512

typedef float f4 __attribute__((ext_vector_type(4)));

__global__ __launch_bounds__(256) void PerPixelConv_kernel(
    const float* __restrict__ kern,   // [B, 9, H, W]
    const float* __restrict__ img,    // [B, 1, H, W]
    float* __restrict__ out)          // [B, 1, H, W]
{
    // Bijective XCD swizzle: 2048 blocks, 8 XCDs, 256-block contiguous chunk each.
    const int bid = ((blockIdx.x & 7) << 8) | (blockIdx.x >> 3);
    int gid = bid * blockDim.x + threadIdx.x;

    const int W8 = PPC_W / 8;                       // 64 8-px slots per row
    const int w8 = (gid & (W8 - 1)) * 8;            // starting w of this thread's 8 pixels
    const int h  = (gid >> 6) & (PPC_H - 1);
    const int b  = gid >> 15;                       // gid / (64*512)

    const size_t plane = (size_t)PPC_H * PPC_W;     // 262144
    const float* kb = kern + (size_t)b * PPC_K2 * plane + (size_t)h * PPC_W + w8;
    const float* ib = img  + (size_t)b * plane;

    // Issue all 18 kernel float4 loads first: HBM-miss stream, max MLP;
    // latency overlaps the (mostly cache-hit) image loads below.
    f4 kv[9][2];
#pragma unroll
    for (int idx = 0; idx < 9; ++idx) {
        kv[idx][0] = *reinterpret_cast<const f4*>(kb + (size_t)idx * plane);
        kv[idx][1] = *reinterpret_cast<const f4*>(kb + (size_t)idx * plane + 4);
    }

    // Image neighborhood rows h-1..h+1, cols w8-1..w8+8 (zero-padded).
    // Per row: two aligned float4s (cols w8..w8+7) + two edge scalars.
    float im[3][10];
#pragma unroll
    for (int r = 0; r < 3; ++r) {
        const int ih = h + r - 1;
        const bool rv = (ih >= 0) && (ih < PPC_H);   // wave-uniform
        const float* row = ib + (size_t)ih * PPC_W;
        f4 c0 = {0.f, 0.f, 0.f, 0.f}, c1 = {0.f, 0.f, 0.f, 0.f};
        float l = 0.f, rr = 0.f;
        if (rv) {
            c0 = *reinterpret_cast<const f4*>(row + w8);
            c1 = *reinterpret_cast<const f4*>(row + w8 + 4);
            if (w8 > 0)            l  = row[w8 - 1];
            if (w8 + 8 < PPC_W)    rr = row[w8 + 8];
        }
        im[r][0] = l;
        im[r][1] = c0.x; im[r][2] = c0.y; im[r][3] = c0.z; im[r][4] = c0.w;
        im[r][5] = c1.x; im[r][6] = c1.y; im[r][7] = c1.z; im[r][8] = c1.w;
        im[r][9] = rr;
    }

    f4 acc0 = {0.f, 0.f, 0.f, 0.f};
    f4 acc1 = {0.f, 0.f, 0.f, 0.f};
#pragma unroll
    for (int kw = 0; kw < 3; ++kw) {
#pragma unroll
        for (int kh = 0; kh < 3; ++kh) {
            const int idx = kw * 3 + kh;
            // output pixel (h, w8+j) uses image[h+kh-1][w8+j+kw-1] = im[kh][j+kw]
            acc0.x = fmaf(kv[idx][0].x, im[kh][0 + kw], acc0.x);
            acc0.y = fmaf(kv[idx][0].y, im[kh][1 + kw], acc0.y);
            acc0.z = fmaf(kv[idx][0].z, im[kh][2 + kw], acc0.z);
            acc0.w = fmaf(kv[idx][0].w, im[kh][3 + kw], acc0.w);
            acc1.x = fmaf(kv[idx][1].x, im[kh][4 + kw], acc1.x);
            acc1.y = fmaf(kv[idx][1].y, im[kh][5 + kw], acc1.y);
            acc1.z = fmaf(kv[idx][1].z, im[kh][6 + kw], acc1.z);
            acc1.w = fmaf(kv[idx][1].w, im[kh][7 + kw], acc1.w);
        }
    }

    float* op = out + (size_t)b * plane + (size_t)h * PPC_W + w8;
    *reinterpret_cast<f4*>(op)     = acc0;
    *reinterpret_cast<f4*>(op + 4) = acc1;
}

extern "C" void kernel_launch(void* const* d_in, const int* in_sizes, int n_in,
                              void* d_out, int out_size, void* d_ws, size_t ws_size,
                              hipStream_t stream) {
    const float* kern = (const float*)d_in[0];  // [16, 9, 512, 512]
    const float* img  = (const float*)d_in[1];  // [16, 1, 512, 512]
    float* out = (float*)d_out;                 // [16, 1, 512, 512]

    const int total = PPC_B * PPC_H * (PPC_W / 8);  // 524,288 threads
    const int block = 256;
    const int grid = total / block;                 // 2048 blocks
    PerPixelConv_kernel<<<grid, block, 0, stream>>>(kern, img, out);
}